// Round 4
// baseline (14322.980 us; speedup 1.0000x reference)
//
#include <hip/hip_runtime.h>
#include <hip/hip_bf16.h>

#define N_LAYERS 1000
#define DD 100
#define DOUT 10
#define TM 64
#define LCHUNK 14336            // bytes per (layer,g) per split: 7ks * 2f * 64lane * 16B
#define SMEM_BYTES 32768        // act_hi 16K | act_lo 16K

typedef short s8v __attribute__((ext_vector_type(8)));
typedef short s4v __attribute__((ext_vector_type(4)));
typedef float f16v __attribute__((ext_vector_type(16)));

__device__ __forceinline__ unsigned short f2bf(float f) {
  __hip_bfloat16 h = __float2bfloat16(f);   // HW RNE convert; compiler packs pairs
  return *reinterpret_cast<unsigned short*>(&h);
}
__device__ __forceinline__ float bf2f(unsigned short h) {
  return __uint_as_float(((unsigned)h) << 16);
}
// [row][k] bf16, 256B row stride; XOR bits 3-6 by row&15 -> 8B slots spread over 16
// positions; only rows r and r+16/r+32/r+48 alias (2-way per 32-row read = near-free).
__device__ __forceinline__ int swz(int row, int kbyte) {
  return (row * 256 + kbyte) ^ ((row & 15) << 3);
}

__device__ __forceinline__ s8v rd8(const char* base, int row, int kbyte) {
  s4v a = *(const s4v*)(base + swz(row, kbyte));
  s4v b = *(const s4v*)(base + swz(row, kbyte + 8));
  return __builtin_shufflevector(a, b, 0, 1, 2, 3, 4, 5, 6, 7);
}
__device__ __forceinline__ void wr8(char* base, int row, int kbyte, s8v v) {
  *(s4v*)(base + swz(row, kbyte))     = __builtin_shufflevector(v, v, 0, 1, 2, 3);
  *(s4v*)(base + swz(row, kbyte + 8)) = __builtin_shufflevector(v, v, 4, 5, 6, 7);
}

// ---------------- prologue: W (f32) + bias -> lane-packed bf16 hi/lo fragments ----------------
// chunk idx = (((L*2+g)*7+ks)*2+f)*64+lane ; 16B at idx*16.
// frag: n = g*64+f*32+(lane&31), k = ks*16+(lane>>5)*8+j ; k==100 holds bias.
__global__ __launch_bounds__(256)
void presplit_kernel(const float* __restrict__ W, const float* __restrict__ b,
                     char* __restrict__ hi_g, char* __restrict__ lo_g) {
  int idx = blockIdx.x * 256 + threadIdx.x;
  if (idx >= N_LAYERS * 2 * 7 * 2 * 64) return;
  int lane = idx & 63;
  int f = (idx >> 6) & 1;
  int r = idx >> 7;
  int ks = r % 7;
  int q = r / 7;
  int g = q & 1;
  int L = q >> 1;
  int n = g * 64 + f * 32 + (lane & 31);
  int k0 = ks * 16 + (lane >> 5) * 8;
  s8v hv, lv;
#pragma unroll
  for (int j = 0; j < 8; ++j) {
    int k = k0 + j;
    float v = 0.0f;
    if (n < DD) {
      if (k < DD) v = W[((size_t)L * DD + n) * DD + k];
      else if (k == DD) v = b[(size_t)L * DD + n];
    }
    unsigned short h = f2bf(v);
    float rr = v - bf2f(h);
    hv[j] = (short)h;
    lv[j] = (short)f2bf(rr);
  }
  *(s8v*)(hi_g + (size_t)idx * 16) = hv;
  *(s8v*)(lo_g + (size_t)idx * 16) = lv;
}

// ---------------- W fragment load: packed (fast) or raw-f32 gather (fallback) ----------------
template <int PRE>
__device__ __forceinline__ void wload(s8v& h, s8v& l, int L, int ks, int wv,
                                      int lane, int l31, int lhi,
                                      const char* __restrict__ whi_g,
                                      const char* __restrict__ wlo_g,
                                      const float* __restrict__ W_g,
                                      const float* __restrict__ b_g) {
  if (PRE) {
    size_t base = (size_t)(L * 2 + (wv >> 1)) * LCHUNK + (size_t)ks * 2048
                + (size_t)(wv & 1) * 1024 + (size_t)lane * 16;
    h = *(const s8v*)(whi_g + base);
    l = *(const s8v*)(wlo_g + base);
  } else {
    int n = wv * 32 + l31;
    int k0 = ks * 16 + lhi * 8;
    s8v hv, lv;
#pragma unroll
    for (int j = 0; j < 8; ++j) {
      int k = k0 + j;
      float v = 0.0f;
      if (n < DD) {
        if (k < DD) v = W_g[((size_t)L * DD + n) * DD + k];
        else if (k == DD) v = b_g[(size_t)L * DD + n];
      }
      unsigned short hh = f2bf(v);
      float rr = v - bf2f(hh);
      hv[j] = (short)hh;
      lv[j] = (short)f2bf(rr);
    }
    h = hv;
    l = lv;
  }
}

// ---------------- main kernel: 1024 wgs, 4 wgs/CU, n-partitioned waves ----------------
// Each wg: 64 batch rows. 4 waves; wave wv owns output channels [wv*32, wv*32+32).
template <int PRE>
__global__ __launch_bounds__(256, 4)
void resnet_main(const float* __restrict__ x_g,
                 const float* __restrict__ W_g, const float* __restrict__ b_g,
                 const float* __restrict__ Wf_g, const float* __restrict__ bf_g,
                 float* __restrict__ out_g,
                 const char* __restrict__ whi_g, const char* __restrict__ wlo_g) {
  extern __shared__ char smem[];
  char* ACT_H = smem;
  char* ACT_L = smem + 16384;

  const int tid = threadIdx.x;
  const int lane = tid & 63;
  const int wv = tid >> 6;
  const int l31 = lane & 31;
  const int lhi = lane >> 5;
  const size_t mbase = (size_t)blockIdx.x * TM;

  // ---- initial activation staging: split(x); k==100 -> 1.0 (bias column), k>100 -> 0 ----
  for (int idx = tid; idx < TM * 16; idx += 256) {
    int m = idx >> 4, kb = idx & 15;
    s8v hv, lv;
#pragma unroll
    for (int j = 0; j < 8; ++j) {
      int k = kb * 8 + j;
      float v = (k < DD) ? x_g[(mbase + m) * DD + k] : (k == DD ? 1.0f : 0.0f);
      unsigned short h = f2bf(v);
      float rr = v - bf2f(h);
      hv[j] = (short)h;
      lv[j] = (short)f2bf(rr);
    }
    wr8(ACT_H, m, kb * 16, hv);
    wr8(ACT_L, m, kb * 16, lv);
  }

  // ---- residual: block input in registers, C-fragment layout ----
  // xr[mi][r] holds x[m = mi*32+l31][n = wv*32 + (r&3)+8*(r>>2)+4*lhi]
  f16v xr[2];
#pragma unroll
  for (int mi = 0; mi < 2; ++mi)
#pragma unroll
    for (int r = 0; r < 16; ++r) {
      int n = wv * 32 + (r & 3) + 8 * (r >> 2) + 4 * lhi;
      int m = mi * 32 + l31;
      xr[mi][r] = (n < DD) ? x_g[(mbase + m) * DD + n] : 0.0f;
    }

  // ---- W double-slot register pipeline: preload ks=0,1 of layer 0 ----
  s8v wh[2], wl[2];
  wload<PRE>(wh[0], wl[0], 0, 0, wv, lane, l31, lhi, whi_g, wlo_g, W_g, b_g);
  wload<PRE>(wh[1], wl[1], 0, 1, wv, lane, l31, lhi, whi_g, wlo_g, W_g, b_g);

  __syncthreads();

  f16v acc[2];

  for (int L = 0; L < N_LAYERS; ++L) {
#pragma unroll
    for (int mi = 0; mi < 2; ++mi)
#pragma unroll
      for (int r = 0; r < 16; ++r) acc[mi][r] = 0.0f;

#pragma unroll
    for (int ks = 0; ks < 7; ++ks) {
      const int s = ks & 1;
      const int kb = ks * 32 + lhi * 16;
      s8v ah0 = rd8(ACT_H, l31, kb);
      s8v ah1 = rd8(ACT_H, 32 + l31, kb);
      s8v al0 = rd8(ACT_L, l31, kb);
      s8v al1 = rd8(ACT_L, 32 + l31, kb);
      acc[0] = __builtin_amdgcn_mfma_f32_32x32x16_bf16(wh[s], ah0, acc[0], 0, 0, 0);
      acc[1] = __builtin_amdgcn_mfma_f32_32x32x16_bf16(wh[s], ah1, acc[1], 0, 0, 0);
      acc[0] = __builtin_amdgcn_mfma_f32_32x32x16_bf16(wh[s], al0, acc[0], 0, 0, 0);
      acc[1] = __builtin_amdgcn_mfma_f32_32x32x16_bf16(wh[s], al1, acc[1], 0, 0, 0);
      acc[0] = __builtin_amdgcn_mfma_f32_32x32x16_bf16(wl[s], ah0, acc[0], 0, 0, 0);
      acc[1] = __builtin_amdgcn_mfma_f32_32x32x16_bf16(wl[s], ah1, acc[1], 0, 0, 0);

      // depth-2 prefetch; cross-layer refill at ks==6
      if (ks < 5) {
        wload<PRE>(wh[s], wl[s], L, ks + 2, wv, lane, l31, lhi, whi_g, wlo_g, W_g, b_g);
      } else if (ks == 6 && L + 1 < N_LAYERS) {
        wload<PRE>(wh[0], wl[0], L + 1, 0, wv, lane, l31, lhi, whi_g, wlo_g, W_g, b_g);
        wload<PRE>(wh[1], wl[1], L + 1, 1, wv, lane, l31, lhi, whi_g, wlo_g, W_g, b_g);
      }
    }

    __syncthreads();   // all act reads done before overwrite

    // ---- epilogue: relu; at block end add register residual and refresh it ----
    const bool bend = ((L % 10) == 9);
#pragma unroll
    for (int mi = 0; mi < 2; ++mi) {
      const int m = mi * 32 + l31;
#pragma unroll
      for (int q = 0; q < 4; ++q) {
        const int n0 = wv * 32 + 8 * q + 4 * lhi;
        const int a = swz(m, n0 * 2);
        if (n0 == 100) {   // bias column: act[100] = 1.0, pads 101..103 = 0
          s4v hq, lq;
          hq[0] = (short)0x3F80; hq[1] = 0; hq[2] = 0; hq[3] = 0;
          lq[0] = 0; lq[1] = 0; lq[2] = 0; lq[3] = 0;
          *(s4v*)(ACT_H + a) = hq;
          *(s4v*)(ACT_L + a) = lq;
        } else {
          s4v hq, lq;
#pragma unroll
          for (int j = 0; j < 4; ++j) {
            const int r = q * 4 + j;
            float o = fmaxf(acc[mi][r], 0.0f);
            if (bend) { o += xr[mi][r]; xr[mi][r] = o; }   // residual add + refresh
            unsigned short h = f2bf(o);
            float rr = o - bf2f(h);
            hq[j] = (short)h;
            lq[j] = (short)f2bf(rr);
          }
          *(s4v*)(ACT_H + a) = hq;
          *(s4v*)(ACT_L + a) = lq;
        }
      }
    }
    __syncthreads();   // writes visible for next layer
  }

  // ---- final projection: out = act @ Wf^T + bf ----
  if (tid < TM) {
    int m = tid;
    float xv[104];
#pragma unroll
    for (int kb = 0; kb < 13; ++kb) {
      s8v h = rd8(ACT_H, m, kb * 16);
      s8v l = rd8(ACT_L, m, kb * 16);
#pragma unroll
      for (int j = 0; j < 8; ++j)
        xv[kb * 8 + j] = bf2f((unsigned short)h[j]) + bf2f((unsigned short)l[j]);
    }
#pragma unroll
    for (int o = 0; o < DOUT; ++o) {
      float s = bf_g[o];
#pragma unroll
      for (int k = 0; k < DD; ++k) s += xv[k] * Wf_g[o * DD + k];
      out_g[(mbase + m) * DOUT + o] = s;
    }
  }
}

extern "C" void kernel_launch(void* const* d_in, const int* in_sizes, int n_in,
                              void* d_out, int out_size, void* d_ws, size_t ws_size,
                              hipStream_t stream) {
  const float* x = (const float*)d_in[0];
  const float* W = (const float*)d_in[1];
  const float* b = (const float*)d_in[2];
  const float* Wf = (const float*)d_in[3];
  const float* bf = (const float*)d_in[4];
  float* out = (float*)d_out;

  const size_t split_bytes = (size_t)N_LAYERS * 2 * LCHUNK;   // 28.672 MB per split
  const size_t need = 2 * split_bytes;                        // 57.344 MB
  const int nwg = 65536 / TM;                                 // 1024
  if (ws_size >= need) {
    char* whi = (char*)d_ws;
    char* wlo = whi + split_bytes;
    const int chunks = N_LAYERS * 2 * 7 * 2 * 64;             // 1,792,000
    presplit_kernel<<<(chunks + 255) / 256, 256, 0, stream>>>(W, b, whi, wlo);
    (void)hipFuncSetAttribute(reinterpret_cast<const void*>(resnet_main<1>),
                              hipFuncAttributeMaxDynamicSharedMemorySize, SMEM_BYTES);
    resnet_main<1><<<nwg, 256, SMEM_BYTES, stream>>>(x, W, b, Wf, bf, out, whi, wlo);
  } else {
    (void)hipFuncSetAttribute(reinterpret_cast<const void*>(resnet_main<0>),
                              hipFuncAttributeMaxDynamicSharedMemorySize, SMEM_BYTES);
    resnet_main<0><<<nwg, 256, SMEM_BYTES, stream>>>(x, W, b, Wf, bf, out, nullptr, nullptr);
  }
}

// Round 5
// 9160.465 us; speedup vs baseline: 1.5636x; 1.5636x over previous
//
#include <hip/hip_runtime.h>
#include <hip/hip_bf16.h>

#define N_LAYERS 1000
#define DD 100
#define DOUT 10
#define TM 64
#define LCHUNK 14336            // bytes per (layer,g) per split: 7ks * 2f * 64lane * 16B
#define SMEM_BYTES 32768        // act_hi 16K | act_lo 16K

typedef short s8v __attribute__((ext_vector_type(8)));
typedef short s4v __attribute__((ext_vector_type(4)));
typedef float f16v __attribute__((ext_vector_type(16)));

__device__ __forceinline__ unsigned short f2bf(float f) {
  __hip_bfloat16 h = __float2bfloat16(f);   // HW RNE convert; compiler packs pairs
  return *reinterpret_cast<unsigned short*>(&h);
}
__device__ __forceinline__ float bf2f(unsigned short h) {
  return __uint_as_float(((unsigned)h) << 16);
}
// [row][k] bf16, 256B row stride; XOR bits 3-6 by row&15 -> 8B slots spread over 16
// positions; only rows r and r+16/r+32/r+48 alias (2-way per 32-row read = near-free).
__device__ __forceinline__ int swz(int row, int kbyte) {
  return (row * 256 + kbyte) ^ ((row & 15) << 3);
}

__device__ __forceinline__ s8v rd8(const char* base, int row, int kbyte) {
  s4v a = *(const s4v*)(base + swz(row, kbyte));
  s4v b = *(const s4v*)(base + swz(row, kbyte + 8));
  return __builtin_shufflevector(a, b, 0, 1, 2, 3, 4, 5, 6, 7);
}
__device__ __forceinline__ void wr8(char* base, int row, int kbyte, s8v v) {
  *(s4v*)(base + swz(row, kbyte))     = __builtin_shufflevector(v, v, 0, 1, 2, 3);
  *(s4v*)(base + swz(row, kbyte + 8)) = __builtin_shufflevector(v, v, 4, 5, 6, 7);
}

// ---------------- prologue: W (f32) + bias -> lane-packed bf16 hi/lo fragments ----------------
// chunk idx = (((L*2+g)*7+ks)*2+f)*64+lane ; 16B at idx*16.
// frag: n = g*64+f*32+(lane&31), k = ks*16+(lane>>5)*8+j ; k==100 holds bias.
__global__ __launch_bounds__(256)
void presplit_kernel(const float* __restrict__ W, const float* __restrict__ b,
                     char* __restrict__ hi_g, char* __restrict__ lo_g) {
  int idx = blockIdx.x * 256 + threadIdx.x;
  if (idx >= N_LAYERS * 2 * 7 * 2 * 64) return;
  int lane = idx & 63;
  int f = (idx >> 6) & 1;
  int r = idx >> 7;
  int ks = r % 7;
  int q = r / 7;
  int g = q & 1;
  int L = q >> 1;
  int n = g * 64 + f * 32 + (lane & 31);
  int k0 = ks * 16 + (lane >> 5) * 8;
  s8v hv, lv;
#pragma unroll
  for (int j = 0; j < 8; ++j) {
    int k = k0 + j;
    float v = 0.0f;
    if (n < DD) {
      if (k < DD) v = W[((size_t)L * DD + n) * DD + k];
      else if (k == DD) v = b[(size_t)L * DD + n];
    }
    unsigned short h = f2bf(v);
    float rr = v - bf2f(h);
    hv[j] = (short)h;
    lv[j] = (short)f2bf(rr);
  }
  *(s8v*)(hi_g + (size_t)idx * 16) = hv;
  *(s8v*)(lo_g + (size_t)idx * 16) = lv;
}

// ---------------- W fragment load: packed (fast) or raw-f32 gather (fallback) ----------------
template <int PRE>
__device__ __forceinline__ void wload(s8v& h, s8v& l, int L, int ks, int wv,
                                      int lane, int l31, int lhi,
                                      const char* __restrict__ whi_g,
                                      const char* __restrict__ wlo_g,
                                      const float* __restrict__ W_g,
                                      const float* __restrict__ b_g) {
  if (PRE) {
    size_t base = (size_t)(L * 2 + (wv >> 1)) * LCHUNK + (size_t)ks * 2048
                + (size_t)(wv & 1) * 1024 + (size_t)lane * 16;
    h = *(const s8v*)(whi_g + base);
    l = *(const s8v*)(wlo_g + base);
  } else {
    int n = wv * 32 + l31;
    int k0 = ks * 16 + lhi * 8;
    s8v hv, lv;
#pragma unroll
    for (int j = 0; j < 8; ++j) {
      int k = k0 + j;
      float v = 0.0f;
      if (n < DD) {
        if (k < DD) v = W_g[((size_t)L * DD + n) * DD + k];
        else if (k == DD) v = b_g[(size_t)L * DD + n];
      }
      unsigned short hh = f2bf(v);
      float rr = v - bf2f(hh);
      hv[j] = (short)hh;
      lv[j] = (short)f2bf(rr);
    }
    h = hv;
    l = lv;
  }
}

// ---------------- main kernel: 1024 wgs, n-partitioned waves ----------------
// Each wg: 64 batch rows. 4 waves; wave wv owns output channels [wv*32, wv*32+32).
// launch_bounds(256,3): ~170-reg budget -> guaranteed no scratch spill (round-4 lesson:
// (256,4)'s 128 budget split 64/64 and spilled 37 GB of scratch traffic).
template <int PRE>
__global__ __launch_bounds__(256, 3)
void resnet_main(const float* __restrict__ x_g,
                 const float* __restrict__ W_g, const float* __restrict__ b_g,
                 const float* __restrict__ Wf_g, const float* __restrict__ bf_g,
                 float* __restrict__ out_g,
                 const char* __restrict__ whi_g, const char* __restrict__ wlo_g) {
  extern __shared__ char smem[];
  char* ACT_H = smem;
  char* ACT_L = smem + 16384;

  const int tid = threadIdx.x;
  const int lane = tid & 63;
  const int wv = tid >> 6;
  const int l31 = lane & 31;
  const int lhi = lane >> 5;
  const size_t mbase = (size_t)blockIdx.x * TM;

  // ---- initial activation staging: split(x); k==100 -> 1.0 (bias column), k>100 -> 0 ----
  for (int idx = tid; idx < TM * 16; idx += 256) {
    int m = idx >> 4, kb = idx & 15;
    s8v hv, lv;
#pragma unroll
    for (int j = 0; j < 8; ++j) {
      int k = kb * 8 + j;
      float v = (k < DD) ? x_g[(mbase + m) * DD + k] : (k == DD ? 1.0f : 0.0f);
      unsigned short h = f2bf(v);
      float rr = v - bf2f(h);
      hv[j] = (short)h;
      lv[j] = (short)f2bf(rr);
    }
    wr8(ACT_H, m, kb * 16, hv);
    wr8(ACT_L, m, kb * 16, lv);
  }

  // ---- residual: block input in registers, C-fragment layout ----
  // xr[mi][r] holds x[m = mi*32+l31][n = wv*32 + (r&3)+8*(r>>2)+4*lhi]
  f16v xr[2];
#pragma unroll
  for (int mi = 0; mi < 2; ++mi)
#pragma unroll
    for (int r = 0; r < 16; ++r) {
      int n = wv * 32 + (r & 3) + 8 * (r >> 2) + 4 * lhi;
      int m = mi * 32 + l31;
      xr[mi][r] = (n < DD) ? x_g[(mbase + m) * DD + n] : 0.0f;
    }

  // ---- W double-slot register pipeline: preload ks=0,1 of layer 0 ----
  s8v wh[2], wl[2];
  wload<PRE>(wh[0], wl[0], 0, 0, wv, lane, l31, lhi, whi_g, wlo_g, W_g, b_g);
  wload<PRE>(wh[1], wl[1], 0, 1, wv, lane, l31, lhi, whi_g, wlo_g, W_g, b_g);

  __syncthreads();

  f16v acc[2];

  for (int L = 0; L < N_LAYERS; ++L) {
#pragma unroll
    for (int mi = 0; mi < 2; ++mi)
#pragma unroll
      for (int r = 0; r < 16; ++r) acc[mi][r] = 0.0f;

#pragma unroll
    for (int ks = 0; ks < 7; ++ks) {
      const int s = ks & 1;
      const int kb = ks * 32 + lhi * 16;
      // per-m-tile grouping: halves live act fragments (reg-pressure control)
      {
        s8v ah0 = rd8(ACT_H, l31, kb);
        s8v al0 = rd8(ACT_L, l31, kb);
        acc[0] = __builtin_amdgcn_mfma_f32_32x32x16_bf16(wh[s], ah0, acc[0], 0, 0, 0);
        acc[0] = __builtin_amdgcn_mfma_f32_32x32x16_bf16(wh[s], al0, acc[0], 0, 0, 0);
        acc[0] = __builtin_amdgcn_mfma_f32_32x32x16_bf16(wl[s], ah0, acc[0], 0, 0, 0);
      }
      {
        s8v ah1 = rd8(ACT_H, 32 + l31, kb);
        s8v al1 = rd8(ACT_L, 32 + l31, kb);
        acc[1] = __builtin_amdgcn_mfma_f32_32x32x16_bf16(wh[s], ah1, acc[1], 0, 0, 0);
        acc[1] = __builtin_amdgcn_mfma_f32_32x32x16_bf16(wh[s], al1, acc[1], 0, 0, 0);
        acc[1] = __builtin_amdgcn_mfma_f32_32x32x16_bf16(wl[s], ah1, acc[1], 0, 0, 0);
      }

      // depth-2 prefetch; cross-layer refill at ks==6
      if (ks < 5) {
        wload<PRE>(wh[s], wl[s], L, ks + 2, wv, lane, l31, lhi, whi_g, wlo_g, W_g, b_g);
      } else if (ks == 6 && L + 1 < N_LAYERS) {
        wload<PRE>(wh[0], wl[0], L + 1, 0, wv, lane, l31, lhi, whi_g, wlo_g, W_g, b_g);
        wload<PRE>(wh[1], wl[1], L + 1, 1, wv, lane, l31, lhi, whi_g, wlo_g, W_g, b_g);
      }
    }

    __syncthreads();   // all act reads done before overwrite

    // ---- epilogue: relu; at block end add register residual and refresh it ----
    const bool bend = ((L % 10) == 9);
#pragma unroll
    for (int mi = 0; mi < 2; ++mi) {
      const int m = mi * 32 + l31;
#pragma unroll
      for (int q = 0; q < 4; ++q) {
        const int n0 = wv * 32 + 8 * q + 4 * lhi;
        const int a = swz(m, n0 * 2);
        if (n0 == 100) {   // bias column: act[100] = 1.0, pads 101..103 = 0
          s4v hq, lq;
          hq[0] = (short)0x3F80; hq[1] = 0; hq[2] = 0; hq[3] = 0;
          lq[0] = 0; lq[1] = 0; lq[2] = 0; lq[3] = 0;
          *(s4v*)(ACT_H + a) = hq;
          *(s4v*)(ACT_L + a) = lq;
        } else {
          s4v hq, lq;
#pragma unroll
          for (int j = 0; j < 4; ++j) {
            const int r = q * 4 + j;
            float o = fmaxf(acc[mi][r], 0.0f);
            if (bend) { o += xr[mi][r]; xr[mi][r] = o; }   // residual add + refresh
            unsigned short h = f2bf(o);
            float rr = o - bf2f(h);
            hq[j] = (short)h;
            lq[j] = (short)f2bf(rr);
          }
          *(s4v*)(ACT_H + a) = hq;
          *(s4v*)(ACT_L + a) = lq;
        }
      }
    }
    __syncthreads();   // writes visible for next layer
  }

  // ---- final projection: out = act @ Wf^T + bf ----
  if (tid < TM) {
    int m = tid;
    float xv[104];
#pragma unroll
    for (int kb = 0; kb < 13; ++kb) {
      s8v h = rd8(ACT_H, m, kb * 16);
      s8v l = rd8(ACT_L, m, kb * 16);
#pragma unroll
      for (int j = 0; j < 8; ++j)
        xv[kb * 8 + j] = bf2f((unsigned short)h[j]) + bf2f((unsigned short)l[j]);
    }
#pragma unroll
    for (int o = 0; o < DOUT; ++o) {
      float s = bf_g[o];
#pragma unroll
      for (int k = 0; k < DD; ++k) s += xv[k] * Wf_g[o * DD + k];
      out_g[(mbase + m) * DOUT + o] = s;
    }
  }
}

extern "C" void kernel_launch(void* const* d_in, const int* in_sizes, int n_in,
                              void* d_out, int out_size, void* d_ws, size_t ws_size,
                              hipStream_t stream) {
  const float* x = (const float*)d_in[0];
  const float* W = (const float*)d_in[1];
  const float* b = (const float*)d_in[2];
  const float* Wf = (const float*)d_in[3];
  const float* bf = (const float*)d_in[4];
  float* out = (float*)d_out;

  const size_t split_bytes = (size_t)N_LAYERS * 2 * LCHUNK;   // 28.672 MB per split
  const size_t need = 2 * split_bytes;                        // 57.344 MB
  const int nwg = 65536 / TM;                                 // 1024
  if (ws_size >= need) {
    char* whi = (char*)d_ws;
    char* wlo = whi + split_bytes;
    const int chunks = N_LAYERS * 2 * 7 * 2 * 64;             // 1,792,000
    presplit_kernel<<<(chunks + 255) / 256, 256, 0, stream>>>(W, b, whi, wlo);
    (void)hipFuncSetAttribute(reinterpret_cast<const void*>(resnet_main<1>),
                              hipFuncAttributeMaxDynamicSharedMemorySize, SMEM_BYTES);
    resnet_main<1><<<nwg, 256, SMEM_BYTES, stream>>>(x, W, b, Wf, bf, out, whi, wlo);
  } else {
    (void)hipFuncSetAttribute(reinterpret_cast<const void*>(resnet_main<0>),
                              hipFuncAttributeMaxDynamicSharedMemorySize, SMEM_BYTES);
    resnet_main<0><<<nwg, 256, SMEM_BYTES, stream>>>(x, W, b, Wf, bf, out, nullptr, nullptr);
  }
}

// Round 6
// 5715.160 us; speedup vs baseline: 2.5061x; 1.6028x over previous
//
#include <hip/hip_runtime.h>
#include <hip/hip_bf16.h>

#define N_LAYERS 1000
#define DD 100
#define DOUT 10
#define TM 64
#define LCHUNK 14336            // bytes per (layer,g) per split: 7ks * 2f * 64lane * 16B
#define SMEM_BYTES 65536        // dbuf: [buf0 H16K|L16K][buf1 H16K|L16K]

typedef short s8v __attribute__((ext_vector_type(8)));
typedef short s4v __attribute__((ext_vector_type(4)));
typedef float f16v __attribute__((ext_vector_type(16)));

__device__ __forceinline__ unsigned short f2bf(float f) {
  __hip_bfloat16 h = __float2bfloat16(f);   // HW RNE convert
  return *reinterpret_cast<unsigned short*>(&h);
}
__device__ __forceinline__ float bf2f(unsigned short h) {
  return __uint_as_float(((unsigned)h) << 16);
}
// [row][k] bf16, 256B row stride; XOR bits 3-6 by row&15 -> 2-way max aliasing on b64
__device__ __forceinline__ int swz(int row, int kbyte) {
  return (row * 256 + kbyte) ^ ((row & 15) << 3);
}

__device__ __forceinline__ s8v rd8(const char* base, int row, int kbyte) {
  s4v a = *(const s4v*)(base + swz(row, kbyte));
  s4v b = *(const s4v*)(base + swz(row, kbyte + 8));
  return __builtin_shufflevector(a, b, 0, 1, 2, 3, 4, 5, 6, 7);
}
__device__ __forceinline__ void wr8(char* base, int row, int kbyte, s8v v) {
  *(s4v*)(base + swz(row, kbyte))     = __builtin_shufflevector(v, v, 0, 1, 2, 3);
  *(s4v*)(base + swz(row, kbyte + 8)) = __builtin_shufflevector(v, v, 4, 5, 6, 7);
}

// ---------------- prologue: W (f32) + bias -> lane-packed bf16 hi/lo fragments ----------------
// byte off = (L*2+g)*LCHUNK + ks*2048 + f*1024 + lane*16
// frag: n = g*64+f*32+(lane&31), k = ks*16+(lane>>5)*8+j ; k==100 holds bias; pads zero.
__global__ __launch_bounds__(256)
void presplit_kernel(const float* __restrict__ W, const float* __restrict__ b,
                     char* __restrict__ hi_g, char* __restrict__ lo_g) {
  int idx = blockIdx.x * 256 + threadIdx.x;
  if (idx >= N_LAYERS * 2 * 7 * 2 * 64) return;
  int lane = idx & 63;
  int f = (idx >> 6) & 1;
  int r = idx >> 7;
  int ks = r % 7;
  int q = r / 7;
  int g = q & 1;
  int L = q >> 1;
  int n = g * 64 + f * 32 + (lane & 31);
  int k0 = ks * 16 + (lane >> 5) * 8;
  s8v hv, lv;
#pragma unroll
  for (int j = 0; j < 8; ++j) {
    int k = k0 + j;
    float v = 0.0f;
    if (n < DD) {
      if (k < DD) v = W[((size_t)L * DD + n) * DD + k];
      else if (k == DD) v = b[(size_t)L * DD + n];
    }
    unsigned short h = f2bf(v);
    float rr = v - bf2f(h);
    hv[j] = (short)h;
    lv[j] = (short)f2bf(rr);
  }
  *(s8v*)(hi_g + (size_t)idx * 16) = hv;
  *(s8v*)(lo_g + (size_t)idx * 16) = lv;
}

// ---------------- W fragment load: packed (fast) or raw-f32 gather (fallback) ----------------
template <int PRE>
__device__ __forceinline__ void wload(s8v& h, s8v& l, int L, int ks, int ni,
                                      int lane, int l31, int lhi,
                                      const char* __restrict__ whi_g,
                                      const char* __restrict__ wlo_g,
                                      const float* __restrict__ W_g,
                                      const float* __restrict__ b_g) {
  if (PRE) {
    size_t base = (size_t)(L * 2 + (ni >> 1)) * LCHUNK + (size_t)ks * 2048
                + (size_t)(ni & 1) * 1024 + (size_t)lane * 16;
    h = *(const s8v*)(whi_g + base);
    l = *(const s8v*)(wlo_g + base);
  } else {
    int n = ni * 32 + l31;
    int k0 = ks * 16 + lhi * 8;
    s8v hv, lv;
#pragma unroll
    for (int j = 0; j < 8; ++j) {
      int k = k0 + j;
      float v = 0.0f;
      if (n < DD) {
        if (k < DD) v = W_g[((size_t)L * DD + n) * DD + k];
        else if (k == DD) v = b_g[(size_t)L * DD + n];
      }
      unsigned short hh = f2bf(v);
      float rr = v - bf2f(hh);
      hv[j] = (short)hh;
      lv[j] = (short)f2bf(rr);
    }
    h = hv;
    l = lv;
  }
}

// ---------------- main kernel: 1024 wgs x 512 thr; 2 wgs/CU (16 waves, 50% occ) ----------------
// wg = 64 batch rows; 8 waves; wave wv: mi = wv&1 (rows mi*32..+32), ni = wv>>1 (ch ni*32..+32).
// Double-buffered act LDS -> ONE barrier per layer.
template <int PRE>
__global__ __launch_bounds__(512, 4)
void resnet_main(const float* __restrict__ x_g,
                 const float* __restrict__ W_g, const float* __restrict__ b_g,
                 const float* __restrict__ Wf_g, const float* __restrict__ bf_g,
                 float* __restrict__ out_g,
                 const char* __restrict__ whi_g, const char* __restrict__ wlo_g) {
  extern __shared__ char smem[];

  const int tid = threadIdx.x;
  const int lane = tid & 63;
  const int wv = tid >> 6;
  const int mi = wv & 1;
  const int ni = wv >> 1;
  const int l31 = lane & 31;
  const int lhi = lane >> 5;
  const size_t mbase = (size_t)blockIdx.x * TM;

  // ---- initial activation staging into buf0: split(x); k==100 -> 1.0; k>100 -> 0 ----
  for (int idx = tid; idx < TM * 16; idx += 512) {
    int m = idx >> 4, kb = idx & 15;
    s8v hv, lv;
#pragma unroll
    for (int j = 0; j < 8; ++j) {
      int k = kb * 8 + j;
      float v = (k < DD) ? x_g[(mbase + m) * DD + k] : (k == DD ? 1.0f : 0.0f);
      unsigned short h = f2bf(v);
      float rr = v - bf2f(h);
      hv[j] = (short)h;
      lv[j] = (short)f2bf(rr);
    }
    wr8(smem, m, kb * 16, hv);            // buf0 H
    wr8(smem + 16384, m, kb * 16, lv);    // buf0 L
  }

  // ---- residual: block input in registers, C-fragment layout of this wave's tile ----
  // xr[r] = x[m = mi*32+l31][n = ni*32 + (r&3)+8*(r>>2)+4*lhi]
  f16v xr;
#pragma unroll
  for (int r = 0; r < 16; ++r) {
    int n = ni * 32 + (r & 3) + 8 * (r >> 2) + 4 * lhi;
    xr[r] = (n < DD) ? x_g[(mbase + mi * 32 + l31) * DD + n] : 0.0f;
  }

  f16v zro;
#pragma unroll
  for (int r = 0; r < 16; ++r) zro[r] = 0.0f;

  // ---- W double-slot register pipeline: preload ks=0,1 of layer 0 ----
  s8v wh[2], wl[2];
  wload<PRE>(wh[0], wl[0], 0, 0, ni, lane, l31, lhi, whi_g, wlo_g, W_g, b_g);
  wload<PRE>(wh[1], wl[1], 0, 1, ni, lane, l31, lhi, whi_g, wlo_g, W_g, b_g);

  __syncthreads();

  int cur = 0;                 // byte offset of current act buffer
  const int arow = mi * 32 + l31;
  f16v acc;

  for (int L = 0; L < N_LAYERS; ++L) {
    const char* AH = smem + cur;
    const char* AL = smem + cur + 16384;
    char* BH = smem + (cur ^ 32768);
    char* BL = smem + (cur ^ 32768) + 16384;

#pragma unroll
    for (int ks = 0; ks < 7; ++ks) {
      const int s = ks & 1;
      const int kb = ks * 32 + lhi * 16;
      s8v ah = rd8(AH, arow, kb);
      s8v al = rd8(AL, arow, kb);
      if (ks == 0) acc = __builtin_amdgcn_mfma_f32_32x32x16_bf16(wh[s], ah, zro, 0, 0, 0);
      else         acc = __builtin_amdgcn_mfma_f32_32x32x16_bf16(wh[s], ah, acc, 0, 0, 0);
      acc = __builtin_amdgcn_mfma_f32_32x32x16_bf16(wh[s], al, acc, 0, 0, 0);
      acc = __builtin_amdgcn_mfma_f32_32x32x16_bf16(wl[s], ah, acc, 0, 0, 0);

      // depth-2 prefetch; cross-layer refill at ks==6
      if (ks < 5) {
        wload<PRE>(wh[s], wl[s], L, ks + 2, ni, lane, l31, lhi, whi_g, wlo_g, W_g, b_g);
      } else if (ks == 6 && L + 1 < N_LAYERS) {
        wload<PRE>(wh[0], wl[0], L + 1, 0, ni, lane, l31, lhi, whi_g, wlo_g, W_g, b_g);
        wload<PRE>(wh[1], wl[1], L + 1, 1, ni, lane, l31, lhi, whi_g, wlo_g, W_g, b_g);
      }
    }

    // ---- epilogue: relu (+residual at block end), split, write to NEXT buffer ----
    const bool bend = ((L % 10) == 9);
#pragma unroll
    for (int q = 0; q < 4; ++q) {
      const int n0 = ni * 32 + 8 * q + 4 * lhi;
      const int a = swz(arow, n0 * 2);
      if (n0 == 100) {   // bias column: act[100] = 1.0, pads 101..103 = 0
        s4v hq, lq;
        hq[0] = (short)0x3F80; hq[1] = 0; hq[2] = 0; hq[3] = 0;
        lq[0] = 0; lq[1] = 0; lq[2] = 0; lq[3] = 0;
        *(s4v*)(BH + a) = hq;
        *(s4v*)(BL + a) = lq;
      } else {
        s4v hq, lq;
#pragma unroll
        for (int j = 0; j < 4; ++j) {
          const int r = q * 4 + j;
          float o = fmaxf(acc[r], 0.0f);
          if (bend) { o += xr[r]; xr[r] = o; }   // residual add + refresh
          unsigned short h = f2bf(o);
          float rr = o - bf2f(h);
          hq[j] = (short)h;
          lq[j] = (short)f2bf(rr);
        }
        *(s4v*)(BH + a) = hq;
        *(s4v*)(BL + a) = lq;
      }
    }

    __syncthreads();   // publish next buffer; single barrier per layer
    cur ^= 32768;
  }

  // ---- final projection: out = act @ Wf^T + bf ----
  if (tid < TM) {
    int m = tid;
    const char* AH = smem + cur;
    const char* AL = smem + cur + 16384;
    float xv[104];
#pragma unroll
    for (int kb = 0; kb < 13; ++kb) {
      s8v h = rd8(AH, m, kb * 16);
      s8v l = rd8(AL, m, kb * 16);
#pragma unroll
      for (int j = 0; j < 8; ++j)
        xv[kb * 8 + j] = bf2f((unsigned short)h[j]) + bf2f((unsigned short)l[j]);
    }
#pragma unroll
    for (int o = 0; o < DOUT; ++o) {
      float s = bf_g[o];
#pragma unroll
      for (int k = 0; k < DD; ++k) s += xv[k] * Wf_g[o * DD + k];
      out_g[(mbase + m) * DOUT + o] = s;
    }
  }
}

extern "C" void kernel_launch(void* const* d_in, const int* in_sizes, int n_in,
                              void* d_out, int out_size, void* d_ws, size_t ws_size,
                              hipStream_t stream) {
  const float* x = (const float*)d_in[0];
  const float* W = (const float*)d_in[1];
  const float* b = (const float*)d_in[2];
  const float* Wf = (const float*)d_in[3];
  const float* bf = (const float*)d_in[4];
  float* out = (float*)d_out;

  const size_t split_bytes = (size_t)N_LAYERS * 2 * LCHUNK;   // 28.672 MB per split
  const size_t need = 2 * split_bytes;                        // 57.344 MB
  const int nwg = 65536 / TM;                                 // 1024
  if (ws_size >= need) {
    char* whi = (char*)d_ws;
    char* wlo = whi + split_bytes;
    const int chunks = N_LAYERS * 2 * 7 * 2 * 64;             // 1,792,000
    presplit_kernel<<<(chunks + 255) / 256, 256, 0, stream>>>(W, b, whi, wlo);
    (void)hipFuncSetAttribute(reinterpret_cast<const void*>(resnet_main<1>),
                              hipFuncAttributeMaxDynamicSharedMemorySize, SMEM_BYTES);
    resnet_main<1><<<nwg, 512, SMEM_BYTES, stream>>>(x, W, b, Wf, bf, out, whi, wlo);
  } else {
    (void)hipFuncSetAttribute(reinterpret_cast<const void*>(resnet_main<0>),
                              hipFuncAttributeMaxDynamicSharedMemorySize, SMEM_BYTES);
    resnet_main<0><<<nwg, 512, SMEM_BYTES, stream>>>(x, W, b, Wf, bf, out, nullptr, nullptr);
  }
}

// Round 7
// 5202.285 us; speedup vs baseline: 2.7532x; 1.0986x over previous
//
#include <hip/hip_runtime.h>
#include <hip/hip_bf16.h>

#define N_LAYERS 1000
#define DD 100
#define DOUT 10
#define TM 64
#define ROWB 264                  // act row stride bytes: 66 words = 2 mod 32 -> 2-way banks (free)
#define PLANE (TM * ROWB)         // 16896 B per plane (H or L)
#define SMEM_BYTES (2 * PLANE)    // 33792 B -> 4 wgs/CU
#define LCHUNK 14336              // packed W bytes per (layer, group) per split
#define LSTRIDE (2 * LCHUNK)      // 28672 B per layer per split

typedef short s4v __attribute__((ext_vector_type(4)));
typedef short s8v __attribute__((ext_vector_type(8)));
typedef float f16v __attribute__((ext_vector_type(16)));

__device__ __forceinline__ unsigned short f2bf(float f) {
  __hip_bfloat16 h = __float2bfloat16(f);   // HW RNE
  return *reinterpret_cast<unsigned short*>(&h);
}
__device__ __forceinline__ float bf2f(unsigned short h) {
  return __uint_as_float(((unsigned)h) << 16);
}

// ---------------- prologue: W (f32) + bias -> lane-packed bf16 hi/lo fragments ----------------
// byte off = (L*2+g)*LCHUNK + ks*2048 + f*1024 + lane*16
// frag: n = g*64+f*32+(lane&31), k = ks*16+(lane>>5)*8+j ; k==100 holds bias; pads zero.
__global__ __launch_bounds__(256)
void presplit_kernel(const float* __restrict__ W, const float* __restrict__ b,
                     char* __restrict__ hi_g, char* __restrict__ lo_g) {
  int idx = blockIdx.x * 256 + threadIdx.x;
  if (idx >= N_LAYERS * 2 * 7 * 2 * 64) return;
  int lane = idx & 63;
  int f = (idx >> 6) & 1;
  int r = idx >> 7;
  int ks = r % 7;
  int q = r / 7;
  int g = q & 1;
  int L = q >> 1;
  int n = g * 64 + f * 32 + (lane & 31);
  int k0 = ks * 16 + (lane >> 5) * 8;
  s8v hv, lv;
#pragma unroll
  for (int j = 0; j < 8; ++j) {
    int k = k0 + j;
    float v = 0.0f;
    if (n < DD) {
      if (k < DD) v = W[((size_t)L * DD + n) * DD + k];
      else if (k == DD) v = b[(size_t)L * DD + n];
    }
    unsigned short h = f2bf(v);
    float rr = v - bf2f(h);
    hv[j] = (short)h;
    lv[j] = (short)f2bf(rr);
  }
  *(s8v*)(hi_g + (size_t)idx * 16) = hv;
  *(s8v*)(lo_g + (size_t)idx * 16) = lv;
}

// ---------------- W fragment load (both f-halves of group g): packed or raw-f32 fallback -----
template <int PRE>
__device__ __forceinline__ void wload(s8v* h, s8v* l,
                                      const char* __restrict__ pH, const char* __restrict__ pL,
                                      int off, int L, int ks, int g, int l31, int lhi,
                                      const float* __restrict__ W_g,
                                      const float* __restrict__ b_g) {
  if (PRE) {
    h[0] = *(const s8v*)(pH + off);
    h[1] = *(const s8v*)(pH + off + 1024);
    l[0] = *(const s8v*)(pL + off);
    l[1] = *(const s8v*)(pL + off + 1024);
  } else {
    int k0 = ks * 16 + lhi * 8;
#pragma unroll
    for (int f = 0; f < 2; ++f) {
      int n = g * 64 + f * 32 + l31;
      s8v hv, lv;
#pragma unroll
      for (int j = 0; j < 8; ++j) {
        int k = k0 + j;
        float v = 0.0f;
        if (n < DD) {
          if (k < DD) v = W_g[((size_t)L * DD + n) * DD + k];
          else if (k == DD) v = b_g[(size_t)L * DD + n];
        }
        unsigned short hh = f2bf(v);
        float rr = v - bf2f(hh);
        hv[j] = (short)hh;
        lv[j] = (short)f2bf(rr);
      }
      h[f] = hv;
      l[f] = lv;
    }
  }
}

// ---------------- main kernel: 1024 wgs x 256 thr, 4 wgs/CU, single resident round ----------
// wg = 64 batch rows, 4 waves. wave wv: mi = wv&1 (rows mi*32+l31), g = wv>>1 (channels
// [g*64, g*64+64) = both f-halves of packed W group g). Single in-place act buffer,
// additive padded layout (no XOR): all LDS ops are base-reg + immediate.
template <int PRE>
__global__ __launch_bounds__(256, 4)
void resnet_main(const float* __restrict__ x_g,
                 const float* __restrict__ W_g, const float* __restrict__ b_g,
                 const float* __restrict__ Wf_g, const float* __restrict__ bf_g,
                 float* __restrict__ out_g,
                 const char* __restrict__ whi_g, const char* __restrict__ wlo_g) {
  extern __shared__ char smem[];

  const int tid = threadIdx.x;
  const int lane = tid & 63;
  const int wv = tid >> 6;
  const int mi = wv & 1;
  const int g = wv >> 1;
  const int l31 = lane & 31;
  const int lhi = lane >> 5;
  const size_t mbase = (size_t)blockIdx.x * TM;
  const int arow = mi * 32 + l31;

  // ---- initial activation staging: split(x); k==100 -> 1.0 (bias col); k>100 -> 0 ----
  for (int idx = tid; idx < TM * 16; idx += 256) {
    int m = idx >> 4, kb = idx & 15;
    s4v h0, h1, l0, l1;
#pragma unroll
    for (int j = 0; j < 8; ++j) {
      int k = kb * 8 + j;
      float v = (k < DD) ? x_g[(mbase + m) * DD + k] : (k == DD ? 1.0f : 0.0f);
      unsigned short hh = f2bf(v);
      float rr = v - bf2f(hh);
      unsigned short ll = f2bf(rr);
      if (j < 4) { h0[j] = (short)hh; l0[j] = (short)ll; }
      else       { h1[j - 4] = (short)hh; l1[j - 4] = (short)ll; }
    }
    char* p = smem + m * ROWB + kb * 16;
    *(s4v*)p = h0;
    *(s4v*)(p + 8) = h1;
    *(s4v*)(p + PLANE) = l0;
    *(s4v*)(p + PLANE + 8) = l1;
  }

  // ---- residual: block input in registers, C-fragment layout of this wave's 2 n-tiles ----
  f16v xr[2];
#pragma unroll
  for (int f = 0; f < 2; ++f)
#pragma unroll
    for (int r = 0; r < 16; ++r) {
      int n = g * 64 + f * 32 + (r & 3) + 8 * (r >> 2) + 4 * lhi;
      xr[f][r] = (n < DD) ? x_g[(mbase + arow) * DD + n] : 0.0f;
    }

  // ---- W double-slot register pipeline: preload ks=0,1 of layer 0 ----
  const char* pH = whi_g + g * LCHUNK + lane * 16;
  const char* pL = wlo_g + g * LCHUNK + lane * 16;
  s8v wh[2][2], wl[2][2];
  wload<PRE>(wh[0], wl[0], pH, pL, 0,    0, 0, g, l31, lhi, W_g, b_g);
  wload<PRE>(wh[1], wl[1], pH, pL, 2048, 0, 1, g, l31, lhi, W_g, b_g);

  __syncthreads();

  // all LDS accesses: these two base registers + compile-time immediates
  const char* rb = smem + arow * ROWB + lhi * 16;              // act reads
  char* wb = smem + arow * ROWB + g * 128 + lhi * 8;           // act writes

  int woff = 0;
  for (int L = 0; L < N_LAYERS; ++L) {
    f16v acc[2];
#pragma unroll
    for (int f = 0; f < 2; ++f)
#pragma unroll
      for (int r = 0; r < 16; ++r) acc[f][r] = 0.0f;

#pragma unroll
    for (int ks = 0; ks < 7; ++ks) {
      const int s = ks & 1;
      s4v a0 = *(const s4v*)(rb + ks * 32);
      s4v a1 = *(const s4v*)(rb + ks * 32 + 8);
      s4v c0 = *(const s4v*)(rb + PLANE + ks * 32);
      s4v c1 = *(const s4v*)(rb + PLANE + ks * 32 + 8);
      s8v ah = __builtin_shufflevector(a0, a1, 0, 1, 2, 3, 4, 5, 6, 7);
      s8v al = __builtin_shufflevector(c0, c1, 0, 1, 2, 3, 4, 5, 6, 7);
      acc[0] = __builtin_amdgcn_mfma_f32_32x32x16_bf16(wh[s][0], ah, acc[0], 0, 0, 0);
      acc[1] = __builtin_amdgcn_mfma_f32_32x32x16_bf16(wh[s][1], ah, acc[1], 0, 0, 0);
      acc[0] = __builtin_amdgcn_mfma_f32_32x32x16_bf16(wh[s][0], al, acc[0], 0, 0, 0);
      acc[1] = __builtin_amdgcn_mfma_f32_32x32x16_bf16(wh[s][1], al, acc[1], 0, 0, 0);
      acc[0] = __builtin_amdgcn_mfma_f32_32x32x16_bf16(wl[s][0], ah, acc[0], 0, 0, 0);
      acc[1] = __builtin_amdgcn_mfma_f32_32x32x16_bf16(wl[s][1], ah, acc[1], 0, 0, 0);

      // depth-2 prefetch; cross-layer refill at ks==6
      if (ks < 5) {
        wload<PRE>(wh[s], wl[s], pH, pL, woff + (ks + 2) * 2048, L, ks + 2, g, l31, lhi, W_g, b_g);
      } else if (ks == 6 && L + 1 < N_LAYERS) {
        wload<PRE>(wh[0], wl[0], pH, pL, woff + LSTRIDE,        L + 1, 0, g, l31, lhi, W_g, b_g);
        wload<PRE>(wh[1], wl[1], pH, pL, woff + LSTRIDE + 2048, L + 1, 1, g, l31, lhi, W_g, b_g);
      }
    }

    __syncthreads();   // all act reads of layer L complete

    // ---- epilogue: relu (+residual at block end), split, in-place write ----
    const bool bend = ((L % 10) == 9);
#pragma unroll
    for (int f = 0; f < 2; ++f) {
#pragma unroll
      for (int q = 0; q < 4; ++q) {
        const int n0 = g * 64 + f * 32 + 8 * q + 4 * lhi;
        char* dst = wb + f * 64 + q * 16;
        if (n0 == 100) {   // bias column: act[100]=1.0, pads 101..103 = 0
          s4v hq, lq;
          hq[0] = (short)0x3F80; hq[1] = 0; hq[2] = 0; hq[3] = 0;
          lq[0] = 0; lq[1] = 0; lq[2] = 0; lq[3] = 0;
          *(s4v*)dst = hq;
          *(s4v*)(dst + PLANE) = lq;
        } else {
          s4v hq, lq;
#pragma unroll
          for (int j = 0; j < 4; ++j) {
            const int r = q * 4 + j;
            float o = fmaxf(acc[f][r], 0.0f);
            if (bend) { o += xr[f][r]; xr[f][r] = o; }
            unsigned short h = f2bf(o);
            float rr = o - bf2f(h);
            hq[j] = (short)h;
            lq[j] = (short)f2bf(rr);
          }
          *(s4v*)dst = hq;
          *(s4v*)(dst + PLANE) = lq;
        }
      }
    }
    __syncthreads();   // writes visible before next layer's reads
    woff += LSTRIDE;
  }

  // ---- final projection: out = act @ Wf^T + bf ----
  if (tid < TM) {
    int m = tid;
    const char* p = smem + m * ROWB;
    float xv[104];
#pragma unroll
    for (int kb = 0; kb < 13; ++kb) {
      s4v h0 = *(const s4v*)(p + kb * 16);
      s4v h1 = *(const s4v*)(p + kb * 16 + 8);
      s4v l0 = *(const s4v*)(p + PLANE + kb * 16);
      s4v l1 = *(const s4v*)(p + PLANE + kb * 16 + 8);
#pragma unroll
      for (int j = 0; j < 4; ++j) {
        xv[kb * 8 + j]     = bf2f((unsigned short)h0[j]) + bf2f((unsigned short)l0[j]);
        xv[kb * 8 + 4 + j] = bf2f((unsigned short)h1[j]) + bf2f((unsigned short)l1[j]);
      }
    }
#pragma unroll
    for (int o = 0; o < DOUT; ++o) {
      float s = bf_g[o];
#pragma unroll
      for (int k = 0; k < DD; ++k) s += xv[k] * Wf_g[o * DD + k];
      out_g[(mbase + m) * DOUT + o] = s;
    }
  }
}

extern "C" void kernel_launch(void* const* d_in, const int* in_sizes, int n_in,
                              void* d_out, int out_size, void* d_ws, size_t ws_size,
                              hipStream_t stream) {
  const float* x = (const float*)d_in[0];
  const float* W = (const float*)d_in[1];
  const float* b = (const float*)d_in[2];
  const float* Wf = (const float*)d_in[3];
  const float* bf = (const float*)d_in[4];
  float* out = (float*)d_out;

  const size_t split_bytes = (size_t)N_LAYERS * 2 * LCHUNK;   // 28.672 MB per split
  const size_t need = 2 * split_bytes;                        // 57.344 MB
  const int nwg = 65536 / TM;                                 // 1024
  if (ws_size >= need) {
    char* whi = (char*)d_ws;
    char* wlo = whi + split_bytes;
    const int chunks = N_LAYERS * 2 * 7 * 2 * 64;             // 1,792,000
    presplit_kernel<<<(chunks + 255) / 256, 256, 0, stream>>>(W, b, whi, wlo);
    (void)hipFuncSetAttribute(reinterpret_cast<const void*>(resnet_main<1>),
                              hipFuncAttributeMaxDynamicSharedMemorySize, SMEM_BYTES);
    resnet_main<1><<<nwg, 256, SMEM_BYTES, stream>>>(x, W, b, Wf, bf, out, whi, wlo);
  } else {
    (void)hipFuncSetAttribute(reinterpret_cast<const void*>(resnet_main<0>),
                              hipFuncAttributeMaxDynamicSharedMemorySize, SMEM_BYTES);
    resnet_main<0><<<nwg, 256, SMEM_BYTES, stream>>>(x, W, b, Wf, bf, out, nullptr, nullptr);
  }
}